// Round 4
// baseline (75.031 us; speedup 1.0000x reference)
//
#include <hip/hip_runtime.h>
#include <hip/hip_cooperative_groups.h>

namespace cg = cooperative_groups;

// Problem dims (fixed): B=8, n=128, d=512, h=1024
constexpr int Bn = 8, Nn = 128, Dd = 512, Hh = 1024;
constexpr int Ff = 2 * Dd;            // 1024
constexpr int KS = 8, KCH = Dd / KS;  // K-split 8, chunk 64

// ws layout (float offsets):
//   v     [0, 1025)
//   alpha [AOFF + (s*Bn+b)*Nn + i]
//   beta  [BOFF + (s*Bn+b)*Nn + j]
//   part  [POFF + ((s*Bn+b)*Nn+i)*Nn + j]
constexpr int AOFF = 2048, BOFF = 10240, POFF = 32768;

__global__ __launch_bounds__(256) void k_fused(const float* __restrict__ A,
                                               const float* __restrict__ Bm,
                                               const float* __restrict__ W1,
                                               const float* __restrict__ b1,
                                               const float* __restrict__ W2,
                                               const float* __restrict__ b2,
                                               float* __restrict__ ws,
                                               float* __restrict__ out) {
    cg::grid_group grid = cg::this_grid();
    const int bid = blockIdx.x;   // 0..255, 1 block per CU
    const int t   = threadIdx.x;

    __shared__ float aw_t[KCH][64];   // k-major: aw_t[k][row] = a*v1
    __shared__ float b_t[KCH][64];
    __shared__ float ared[4][64];
    __shared__ float bred[4][64];

    // ================= Phase 1: v[f] = W1[f,:].W2 ; v[Ff] = b1.W2 + b2 ====
    {
        const int wave = (bid << 2) + (t >> 6);   // 0..1023 == Ff rows
        const int lane = t & 63;
        const float4* w4 = (const float4*)W2;
        const float4* r4 = (const float4*)(W1 + (size_t)wave * Hh);
        float p = 0.f;
#pragma unroll
        for (int q = 0; q < Hh / 256; ++q) {
            float4 x = r4[lane + 64 * q], y = w4[lane + 64 * q];
            p = fmaf(x.x, y.x, p); p = fmaf(x.y, y.y, p);
            p = fmaf(x.z, y.z, p); p = fmaf(x.w, y.w, p);
        }
#pragma unroll
        for (int off = 32; off; off >>= 1) p += __shfl_down(p, off);
        if (lane == 0) ws[wave] = p;
        if (wave == 0) {                           // block 0 wave 0: the c row
            const float4* c4 = (const float4*)b1;
            float p2 = 0.f;
#pragma unroll
            for (int q = 0; q < Hh / 256; ++q) {
                float4 x = c4[lane + 64 * q], y = w4[lane + 64 * q];
                p2 = fmaf(x.x, y.x, p2); p2 = fmaf(x.y, y.y, p2);
                p2 = fmaf(x.z, y.z, p2); p2 = fmaf(x.w, y.w, p2);
            }
#pragma unroll
            for (int off = 32; off; off >>= 1) p2 += __shfl_down(p2, off);
            if (lane == 0) ws[Ff] = p2 + b2[0];
        }
    }
    grid.sync();

    // ================= Phase 2: bilinear partials (K-split 8) =============
    {
        const int s     = bid >> 5;
        const int rem   = bid & 31;
        const int batch = rem >> 2;
        const int it    = (rem >> 1) & 1, jt = rem & 1;
        const int K0    = s * KCH;

        const int row = t & 63, c0 = t >> 6;
        const float* arow = A  + (size_t)(batch * Nn + it * 64 + row) * Dd + K0;
        const float* brow = Bm + (size_t)(batch * Nn + jt * 64 + row) * Dd + K0;
        const float4* w1p = (const float4*)(ws + K0);
        const float4* w2p = (const float4*)(ws + Dd + K0);

        float alp = 0.f, bep = 0.f;
#pragma unroll
        for (int q = 0; q < 4; ++q) {
            const int f4 = c0 + 4 * q;
            float4 av = ((const float4*)arow)[f4];
            float4 bv = ((const float4*)brow)[f4];
            float4 w1 = w1p[f4];
            float4 w2 = w2p[f4];
            alp = fmaf(av.x, w2.x, alp); alp = fmaf(av.y, w2.y, alp);
            alp = fmaf(av.z, w2.z, alp); alp = fmaf(av.w, w2.w, alp);
            bep = fmaf(bv.x, w2.x, bep); bep = fmaf(bv.y, w2.y, bep);
            bep = fmaf(bv.z, w2.z, bep); bep = fmaf(bv.w, w2.w, bep);
            const int k = 4 * f4;
            aw_t[k + 0][row] = av.x * w1.x;   // wave-uniform k, row=lane: no conflict
            aw_t[k + 1][row] = av.y * w1.y;
            aw_t[k + 2][row] = av.z * w1.z;
            aw_t[k + 3][row] = av.w * w1.w;
            b_t[k + 0][row] = bv.x;
            b_t[k + 1][row] = bv.y;
            b_t[k + 2][row] = bv.z;
            b_t[k + 3][row] = bv.w;
        }
        ared[c0][row] = alp;
        bred[c0][row] = bep;
        __syncthreads();

        if (jt == 0 && t < 64) {
            ws[AOFF + (s * Bn + batch) * Nn + it * 64 + t] =
                ared[0][t] + ared[1][t] + ared[2][t] + ared[3][t];
        }
        if (it == 0 && t >= 64 && t < 128) {
            const int j = t - 64;
            ws[BOFF + (s * Bn + batch) * Nn + jt * 64 + j] =
                bred[0][j] + bred[1][j] + bred[2][j] + bred[3][j];
        }

        const int tr = t >> 4, tc = t & 15;
        float acc00 = 0.f, acc01 = 0.f, acc02 = 0.f, acc03 = 0.f;
        float acc10 = 0.f, acc11 = 0.f, acc12 = 0.f, acc13 = 0.f;
        float acc20 = 0.f, acc21 = 0.f, acc22 = 0.f, acc23 = 0.f;
        float acc30 = 0.f, acc31 = 0.f, acc32 = 0.f, acc33 = 0.f;

#pragma unroll 8
        for (int k = 0; k < KCH; ++k) {
            const float4 av = *(const float4*)&aw_t[k][4 * tr];
            const float4 bv = *(const float4*)&b_t[k][4 * tc];
            acc00 = fmaf(av.x, bv.x, acc00); acc01 = fmaf(av.x, bv.y, acc01);
            acc02 = fmaf(av.x, bv.z, acc02); acc03 = fmaf(av.x, bv.w, acc03);
            acc10 = fmaf(av.y, bv.x, acc10); acc11 = fmaf(av.y, bv.y, acc11);
            acc12 = fmaf(av.y, bv.z, acc12); acc13 = fmaf(av.y, bv.w, acc13);
            acc20 = fmaf(av.z, bv.x, acc20); acc21 = fmaf(av.z, bv.y, acc21);
            acc22 = fmaf(av.z, bv.z, acc22); acc23 = fmaf(av.z, bv.w, acc23);
            acc30 = fmaf(av.w, bv.x, acc30); acc31 = fmaf(av.w, bv.y, acc31);
            acc32 = fmaf(av.w, bv.z, acc32); acc33 = fmaf(av.w, bv.w, acc33);
        }

        float* p = ws + POFF +
                   ((size_t)((s * Bn + batch) * Nn + it * 64 + 4 * tr)) * Nn +
                   jt * 64 + 4 * tc;
        *(float4*)(p + 0 * Nn) = make_float4(acc00, acc01, acc02, acc03);
        *(float4*)(p + 1 * Nn) = make_float4(acc10, acc11, acc12, acc13);
        *(float4*)(p + 2 * Nn) = make_float4(acc20, acc21, acc22, acc23);
        *(float4*)(p + 3 * Nn) = make_float4(acc30, acc31, acc32, acc33);
    }
    grid.sync();

    // ================= Phase 3: reduce over K-splits + alpha - beta + c ===
    if (t < 128) {
        const int idx = bid * 128 + t;           // float4 index, 0..32767
        const int j4 = idx & 31;
        const int i  = (idx >> 5) & 127;
        const int b  = idx >> 12;

        float sx = 0.f, sy = 0.f, sz = 0.f, sw = 0.f, asum = 0.f;
        float bx = 0.f, by = 0.f, bz = 0.f, bw = 0.f;
#pragma unroll
        for (int s = 0; s < KS; ++s) {
            const float4 p = *(const float4*)&ws[POFF +
                ((size_t)((s * Bn + b) * Nn + i)) * Nn + 4 * j4];
            sx += p.x; sy += p.y; sz += p.z; sw += p.w;
            asum += ws[AOFF + (s * Bn + b) * Nn + i];
            const float4 bb = *(const float4*)&ws[BOFF + (s * Bn + b) * Nn + 4 * j4];
            bx += bb.x; by += bb.y; bz += bb.z; bw += bb.w;
        }
        const float c = ws[Ff];
        float4 o;
        o.x = sx + asum - bx + c;
        o.y = sy + asum - by + c;
        o.z = sz + asum - bz + c;
        o.w = sw + asum - bw + c;
        *(float4*)&out[((size_t)(b * Nn + i)) * Nn + 4 * j4] = o;
    }
}

extern "C" void kernel_launch(void* const* d_in, const int* in_sizes, int n_in,
                              void* d_out, int out_size, void* d_ws, size_t ws_size,
                              hipStream_t stream) {
    const float* a  = (const float*)d_in[0];
    const float* b  = (const float*)d_in[1];
    const float* W1 = (const float*)d_in[2];
    const float* b1 = (const float*)d_in[3];
    const float* W2 = (const float*)d_in[4];
    const float* b2 = (const float*)d_in[5];
    float* out = (float*)d_out;
    float* ws  = (float*)d_ws;

    void* args[] = {(void*)&a, (void*)&b, (void*)&W1, (void*)&b1,
                    (void*)&W2, (void*)&b2, (void*)&ws, (void*)&out};
    hipLaunchCooperativeKernel((const void*)k_fused, dim3(256), dim3(256),
                               args, 0, stream);
}

// Round 5
// 24.018 us; speedup vs baseline: 3.1239x; 3.1239x over previous
//
#include <hip/hip_runtime.h>

// Problem dims (fixed): B=8, n=128, d=512, h=1024
constexpr int Bn = 8, Nn = 128, Dd = 512, Hh = 1024;
constexpr int KS = 32, KCH = Dd / KS;   // K-split 32, chunk 16

// ws layout (float offsets):
//   alpha [AOFF + (s*Bn+b)*Nn + i]      32*8*128
//   beta  [BOFF + (s*Bn+b)*Nn + j]      32*8*128
//   part  [POFF + ((s*Bn+b)*Nn+i)*Nn+j] 32*8*128*128 (16 MB)
constexpr int AOFF = 0, BOFF = 32768, POFF = 65536;

// ---------------------------------------------------------------------------
// Kernel 1: per-block v-chunk compute + bilinear partial for a full 128x128
// tile over 16 k's. Grid (32 s, 8 b) x 256 threads.
// ---------------------------------------------------------------------------
__global__ __launch_bounds__(256) void k_bil(const float* __restrict__ A,
                                             const float* __restrict__ Bm,
                                             const float* __restrict__ W1,
                                             const float* __restrict__ W2,
                                             float* __restrict__ ws) {
    __shared__ float v1_s[KCH], v2_s[KCH];
    __shared__ float aw_t[KCH][Nn];     // k-major premultiplied a*v1
    __shared__ float b_t[KCH][Nn];      // k-major raw b
    __shared__ float apart[4][Nn];
    __shared__ float bpart[4][Nn];

    const int s = blockIdx.x, b = blockIdx.y;
    const int t = threadIdx.x;
    const int K0 = s * KCH;

    // ---- Phase A: v chunk = W1[rows,:] . W2  (32 rows, 8 threads/row)
    {
        const int rr = t >> 3, lane8 = t & 7;
        const int frow = (rr < KCH) ? (K0 + rr) : (Dd + K0 + (rr - KCH));
        const float4* r4 = (const float4*)(W1 + (size_t)frow * Hh);
        const float4* w4 = (const float4*)W2;
        float p = 0.f;
#pragma unroll
        for (int q = 0; q < 32; ++q) {
            const int i4 = lane8 + 8 * q;
            float4 x = r4[i4], y = w4[i4];
            p = fmaf(x.x, y.x, p); p = fmaf(x.y, y.y, p);
            p = fmaf(x.z, y.z, p); p = fmaf(x.w, y.w, p);
        }
        p += __shfl_xor(p, 4); p += __shfl_xor(p, 2); p += __shfl_xor(p, 1);
        if (lane8 == 0) {
            if (rr < KCH) v1_s[rr] = p;
            else          v2_s[rr - KCH] = p;
        }
    }
    __syncthreads();

    // ---- Phase B: stage aw = a*v1 and raw b, k-major; alpha/beta partials
#pragma unroll
    for (int rep = 0; rep < 2; ++rep) {
        const int idx = t + 256 * rep;       // 0..511
        const int row = idx & 127;
        const int q   = idx >> 7;            // 0..3  (k-quad)
        float4 av = *(const float4*)(A  + ((size_t)(b * Nn + row)) * Dd + K0 + 4 * q);
        float4 bv = *(const float4*)(Bm + ((size_t)(b * Nn + row)) * Dd + K0 + 4 * q);
        const float w20 = v2_s[4 * q], w21 = v2_s[4 * q + 1];
        const float w22 = v2_s[4 * q + 2], w23 = v2_s[4 * q + 3];
        float ap = av.x * w20 + av.y * w21 + av.z * w22 + av.w * w23;
        float bp = bv.x * w20 + bv.y * w21 + bv.z * w22 + bv.w * w23;
        apart[q][row] = ap;
        bpart[q][row] = bp;
        aw_t[4 * q + 0][row] = av.x * v1_s[4 * q + 0];
        aw_t[4 * q + 1][row] = av.y * v1_s[4 * q + 1];
        aw_t[4 * q + 2][row] = av.z * v1_s[4 * q + 2];
        aw_t[4 * q + 3][row] = av.w * v1_s[4 * q + 3];
        b_t[4 * q + 0][row] = bv.x;
        b_t[4 * q + 1][row] = bv.y;
        b_t[4 * q + 2][row] = bv.z;
        b_t[4 * q + 3][row] = bv.w;
    }
    __syncthreads();

    // alpha/beta chunk-partials to global
    if (t < 128) {
        ws[AOFF + (s * Bn + b) * Nn + t] =
            apart[0][t] + apart[1][t] + apart[2][t] + apart[3][t];
    } else {
        const int j = t - 128;
        ws[BOFF + (s * Bn + b) * Nn + j] =
            bpart[0][j] + bpart[1][j] + bpart[2][j] + bpart[3][j];
    }

    // ---- Phase C: 8x8 micro-tile. rows 8*tr.., cols {2tc,2tc+1}+32m
    const int tr = t >> 4, tc = t & 15;
    float2 acc[8][4];
#pragma unroll
    for (int r = 0; r < 8; ++r)
#pragma unroll
        for (int m = 0; m < 4; ++m) acc[r][m] = make_float2(0.f, 0.f);

#pragma unroll
    for (int kk = 0; kk < KCH; ++kk) {
        const float4 a0 = *(const float4*)&aw_t[kk][8 * tr];
        const float4 a1 = *(const float4*)&aw_t[kk][8 * tr + 4];
        float2 bvv[4];
#pragma unroll
        for (int m = 0; m < 4; ++m)
            bvv[m] = *(const float2*)&b_t[kk][2 * tc + 32 * m];
        const float ar[8] = {a0.x, a0.y, a0.z, a0.w, a1.x, a1.y, a1.z, a1.w};
#pragma unroll
        for (int r = 0; r < 8; ++r)
#pragma unroll
            for (int m = 0; m < 4; ++m) {
                acc[r][m].x = fmaf(ar[r], bvv[m].x, acc[r][m].x);
                acc[r][m].y = fmaf(ar[r], bvv[m].y, acc[r][m].y);
            }
    }

    // partial writes
    float* pb = ws + POFF + ((size_t)(s * Bn + b) * Nn + 8 * tr) * Nn + 2 * tc;
#pragma unroll
    for (int r = 0; r < 8; ++r)
#pragma unroll
        for (int m = 0; m < 4; ++m)
            *(float2*)(pb + (size_t)r * Nn + 32 * m) = acc[r][m];
}

// ---------------------------------------------------------------------------
// Kernel 2: out[b,i,j] = sum_s part + alpha[b,i] - beta[b,j] + c
// Grid (16 i-chunks, 8 b) x 256 threads. c computed in-kernel by wave 3.
// ---------------------------------------------------------------------------
__global__ __launch_bounds__(256) void k_red(const float* __restrict__ ws,
                                             const float* __restrict__ b1,
                                             const float* __restrict__ W2,
                                             const float* __restrict__ b2,
                                             float* __restrict__ out) {
    __shared__ float bs[Nn];
    __shared__ float as[8];
    __shared__ float cs;

    const int ic = blockIdx.x, b = blockIdx.y;
    const int i0 = 8 * ic;
    const int t = threadIdx.x;

    if (t < 128) {                       // beta sums, all 128 j
        float v = 0.f;
#pragma unroll
        for (int s = 0; s < KS; ++s) v += ws[BOFF + (s * Bn + b) * Nn + t];
        bs[t] = v;
    } else if (t < 136) {                // alpha sums for this block's 8 rows
        const int r = t - 128;
        float v = 0.f;
#pragma unroll
        for (int s = 0; s < KS; ++s) v += ws[AOFF + (s * Bn + b) * Nn + i0 + r];
        as[r] = v;
    } else if (t >= 192) {               // wave 3: c = b1.W2 + b2
        const int lane = t - 192;
        const float4* c4 = (const float4*)b1;
        const float4* w4 = (const float4*)W2;
        float p = 0.f;
#pragma unroll
        for (int q = 0; q < 4; ++q) {
            float4 x = c4[lane + 64 * q], y = w4[lane + 64 * q];
            p = fmaf(x.x, y.x, p); p = fmaf(x.y, y.y, p);
            p = fmaf(x.z, y.z, p); p = fmaf(x.w, y.w, p);
        }
#pragma unroll
        for (int off = 32; off; off >>= 1) p += __shfl_down(p, off);
        if (lane == 0) cs = p + b2[0];
    }
    __syncthreads();

    const int r2 = t >> 5, c4i = t & 31;  // row i0+r2, cols 4*c4i..
    const int i = i0 + r2;
    float4 o = make_float4(0.f, 0.f, 0.f, 0.f);
#pragma unroll
    for (int s = 0; s < KS; ++s) {
        const float4 p = *(const float4*)&ws[POFF +
            ((size_t)((s * Bn + b) * Nn + i)) * Nn + 4 * c4i];
        o.x += p.x; o.y += p.y; o.z += p.z; o.w += p.w;
    }
    const float al = as[r2], c = cs;
    o.x += al - bs[4 * c4i + 0] + c;
    o.y += al - bs[4 * c4i + 1] + c;
    o.z += al - bs[4 * c4i + 2] + c;
    o.w += al - bs[4 * c4i + 3] + c;
    *(float4*)&out[((size_t)(b * Nn + i)) * Nn + 4 * c4i] = o;
}

extern "C" void kernel_launch(void* const* d_in, const int* in_sizes, int n_in,
                              void* d_out, int out_size, void* d_ws, size_t ws_size,
                              hipStream_t stream) {
    const float* a  = (const float*)d_in[0];
    const float* b  = (const float*)d_in[1];
    const float* W1 = (const float*)d_in[2];
    const float* b1 = (const float*)d_in[3];
    const float* W2 = (const float*)d_in[4];
    const float* b2 = (const float*)d_in[5];
    float* out = (float*)d_out;
    float* ws  = (float*)d_ws;

    dim3 g1(KS, Bn);                    // (32, 8) = 256 blocks, s fastest -> XCD share
    k_bil<<<g1, 256, 0, stream>>>(a, b, W1, W2, ws);

    dim3 g2(16, Bn);                    // (16, 8) = 128 blocks
    k_red<<<g2, 256, 0, stream>>>(ws, b1, W2, b2, out);
}